// Round 4
// baseline (337.901 us; speedup 1.0000x reference)
//
#include <hip/hip_runtime.h>

#define NUM_C 512
#define HW    32768     // 128*256
#define K     19
#define NT    256
#define CP    (NUM_C + 4)
#define CH    16        // pixel chunks per (b, mtile)

typedef __attribute__((ext_vector_type(4))) float        f32x4;
typedef __attribute__((ext_vector_type(8))) short        bf16x8;
typedef __attribute__((ext_vector_type(4))) unsigned int u32x4;

// fp32 -> packed (hi_bf16 | lo_bf16<<16); hi = truncation, lo = RNE(x - hi).
// x == hi + lo to ~2^-16 relative; exact enough for the 2%-rel loss threshold.
__device__ __forceinline__ unsigned int cvt_hilo(float x) {
    unsigned int u  = __float_as_uint(x);
    float        d  = x - __uint_as_float(u & 0xFFFF0000u);   // exact residual
    unsigned int v  = __float_as_uint(d);
    unsigned int lo = (v + 0x7FFFu + ((v >> 16) & 1u)) & 0xFFFF0000u;  // RNE bf16
    return (u >> 16) | lo;     // low short = hi (k-slot 2p), high short = lo (2p+1)
}

// ---------------------------------------------------------------------------
// K1: sums[b,c,k] = sum_hw feat * onehot(lbl) as an MFMA GEMM.
// A (16 ch x 32 k-slots) = hi/lo bf16 of 16 pixels; B = one-hot rows
// duplicated per hi/lo slot (exact in bf16). Two N-tiles cover 19 classes.
// grid = 2 batches x 32 mtiles x 16 chunks = 1024 blocks x 256 thr (4 waves).
// Each wave: 512 pixels = 32 MFMA steps; 4 MFMA/step (S,T x n0,n1).
// Verified layouts (m89/m91/m118): A[m=lane&15][k=(lane>>4)*8+j],
// C/D col=lane&15, row=(lane>>4)*4+reg.
// ---------------------------------------------------------------------------
__global__ __launch_bounds__(NT, 4) void seg_sum_mfma(
    const float* __restrict__ S, const float* __restrict__ T,
    const int* __restrict__ lbl,
    float* __restrict__ sumsS, float* __restrict__ sumsT)
{
    const int tid  = threadIdx.x;
    const int lane = tid & 63, wv = tid >> 6;
    const int bid  = blockIdx.x;
    const int chunk = bid & (CH - 1);
    const int mtile = (bid >> 4) & 31;
    const int b     = bid >> 9;

    const int n   = lane & 15;    // class col (tile0) / channel row-in-tile
    const int q   = lane >> 4;    // k-group
    const int n16 = n + 16;       // class col for tile1

    const int c = mtile * 16 + n;
    const float* rowS = S + (size_t)(b * NUM_C + c) * HW;
    const float* rowT = T + (size_t)(b * NUM_C + c) * HW;
    const int*   lrow = lbl + (size_t)b * HW;

    f32x4 accS0 = {0.f,0.f,0.f,0.f}, accS1 = {0.f,0.f,0.f,0.f};
    f32x4 accT0 = {0.f,0.f,0.f,0.f}, accT1 = {0.f,0.f,0.f,0.f};

    const int pw = chunk * (HW / CH) + wv * (HW / CH / 4);  // wave's 512-pixel range

    for (int s = 0; s < 32; ++s) {
        const int p0 = pw + s * 16;
        const int fi = (p0 >> 2) + q;            // float4 / int4 index (16B aligned)
        f32x4 xs = ((const f32x4*)rowS)[fi];
        f32x4 xt = ((const f32x4*)rowT)[fi];
        int4  lv = ((const int4*)lrow)[fi];

        u32x4 ua, ub;
        ua.x = cvt_hilo(xs.x); ua.y = cvt_hilo(xs.y);
        ua.z = cvt_hilo(xs.z); ua.w = cvt_hilo(xs.w);
        ub.x = cvt_hilo(xt.x); ub.y = cvt_hilo(xt.y);
        ub.z = cvt_hilo(xt.z); ub.w = cvt_hilo(xt.w);
        bf16x8 aS = __builtin_bit_cast(bf16x8, ua);
        bf16x8 aT = __builtin_bit_cast(bf16x8, ub);

        u32x4 w0, w1;   // one-hot, duplicated into both bf16 halves (hi & lo slot)
        w0.x = (lv.x == n)   ? 0x3F803F80u : 0u;
        w0.y = (lv.y == n)   ? 0x3F803F80u : 0u;
        w0.z = (lv.z == n)   ? 0x3F803F80u : 0u;
        w0.w = (lv.w == n)   ? 0x3F803F80u : 0u;
        w1.x = (lv.x == n16) ? 0x3F803F80u : 0u;
        w1.y = (lv.y == n16) ? 0x3F803F80u : 0u;
        w1.z = (lv.z == n16) ? 0x3F803F80u : 0u;
        w1.w = (lv.w == n16) ? 0x3F803F80u : 0u;
        bf16x8 fb0 = __builtin_bit_cast(bf16x8, w0);
        bf16x8 fb1 = __builtin_bit_cast(bf16x8, w1);

        accS0 = __builtin_amdgcn_mfma_f32_16x16x32_bf16(aS, fb0, accS0, 0, 0, 0);
        accS1 = __builtin_amdgcn_mfma_f32_16x16x32_bf16(aS, fb1, accS1, 0, 0, 0);
        accT0 = __builtin_amdgcn_mfma_f32_16x16x32_bf16(aT, fb0, accT0, 0, 0, 0);
        accT1 = __builtin_amdgcn_mfma_f32_16x16x32_bf16(aT, fb1, accT1, 0, 0, 0);
    }

    // ---- cross-wave reduce in LDS, then one global atomicAdd per element ----
    // per-wave layout: [0,256) S-tile0 (row*16+col), [256,304) S-tile1 (row*3+col'),
    // [304,560) T-tile0, [560,608) T-tile1
    __shared__ float red[4][608];
#pragma unroll
    for (int r = 0; r < 4; ++r) {
        int row = q * 4 + r;
        red[wv][row * 16 + n]       = accS0[r];
        red[wv][304 + row * 16 + n] = accT0[r];
    }
    if (n < 3) {
#pragma unroll
        for (int r = 0; r < 4; ++r) {
            int row = q * 4 + r;
            red[wv][256 + row * 3 + n]       = accS1[r];
            red[wv][560 + row * 3 + n]       = accT1[r];
        }
    }
    __syncthreads();

    for (int t = tid; t < 608; t += NT) {
        float v = red[0][t] + red[1][t] + red[2][t] + red[3][t];
        int tensor = t / 304;
        int r = t - tensor * 304;
        int row, col;
        if (r < 256) { row = r >> 4; col = r & 15; }
        else         { int rr = r - 256; row = rr / 3; col = 16 + (rr - (rr / 3) * 3); }
        float* dst = (tensor ? sumsT : sumsS)
                   + (size_t)(b * NUM_C + mtile * 16 + row) * K + col;
        atomicAdd(dst, v);   // 16 chunk-writers per address
    }
}

// ---------------------------------------------------------------------------
// K2: grid = 8 blocks = 2 batches x 4 slices. Each block redundantly builds
// counts + centers + diagonal norms, then 361 pair-tasks interleaved over
// slices; each task computes both dots, normalizes, accumulates (dS-dT)^2.
// ---------------------------------------------------------------------------
__global__ __launch_bounds__(NT, 4) void finalize_kernel(
    const float* __restrict__ sumsS, const float* __restrict__ sumsT,
    const int* __restrict__ lbl, float* __restrict__ out)
{
    __shared__ float centS[K * CP];
    __shared__ float centT[K * CP];
    __shared__ float cntf[K];
    __shared__ float nrm[2 * K];
    __shared__ float red[NT];
    __shared__ int   redc[4 * K];
    const int tid   = threadIdx.x;
    const int b     = blockIdx.x >> 2;
    const int slice = blockIdx.x & 3;

    // exact label counts (branchless, register histogram)
    int cnt[K];
#pragma unroll
    for (int k = 0; k < K; ++k) cnt[k] = 0;
    const int4* L4 = (const int4*)(lbl + (size_t)b * HW);
    for (int i = tid; i < HW / 4; i += NT) {
        int4 l = L4[i];
#pragma unroll
        for (int k = 0; k < K; ++k)
            cnt[k] += (l.x == k) + (l.y == k) + (l.z == k) + (l.w == k);
    }
    const int lane = tid & 63, wv = tid >> 6;
#pragma unroll
    for (int k = 0; k < K; ++k) {
        int v = cnt[k];
#pragma unroll
        for (int off = 32; off > 0; off >>= 1) v += __shfl_down(v, off);
        if (lane == 0) redc[wv * K + k] = v;
    }
    __syncthreads();
    if (tid < K)
        cntf[tid] = (float)(redc[tid] + redc[K + tid] + redc[2 * K + tid] + redc[3 * K + tid]) + 1e-6f;
    __syncthreads();

    // centers, [k][c] padded layout
    for (int j = tid; j < NUM_C * K; j += NT) {
        int c = j / K, k = j - (j / K) * K;
        float cn = cntf[k];
        size_t gi = (size_t)(b * NUM_C + c) * K + k;
        centS[k * CP + c] = sumsS[gi] / cn;
        centT[k * CP + c] = sumsT[gi] / cn;
    }
    __syncthreads();

    // diagonal norms
    if (tid < 2 * K) {
        const float4* A = (const float4*)((tid < K ? centS : centT) + (tid < K ? tid : tid - K) * CP);
        float d = 0.f;
        for (int c = 0; c < NUM_C / 4; ++c) {
            float4 x = A[c];
            d = fmaf(x.x, x.x, d); d = fmaf(x.y, x.y, d);
            d = fmaf(x.z, x.z, d); d = fmaf(x.w, x.w, d);
        }
        nrm[tid] = fmaxf(sqrtf(d), 1e-8f);
    }
    __syncthreads();

    float acc = 0.f;
    int t = tid * 4 + slice;
    if (t < K * K) {
        int i = t / K, j = t - (t / K) * K;
        const float4* Si = (const float4*)(centS + i * CP);
        const float4* Sj = (const float4*)(centS + j * CP);
        const float4* Ti = (const float4*)(centT + i * CP);
        const float4* Tj = (const float4*)(centT + j * CP);
        float ds = 0.f, dt = 0.f;
        for (int c = 0; c < NUM_C / 4; ++c) {
            float4 xs = Si[c], ys = Sj[c];
            float4 xt = Ti[c], yt = Tj[c];
            ds = fmaf(xs.x, ys.x, ds); ds = fmaf(xs.y, ys.y, ds);
            ds = fmaf(xs.z, ys.z, ds); ds = fmaf(xs.w, ys.w, ds);
            dt = fmaf(xt.x, yt.x, dt); dt = fmaf(xt.y, yt.y, dt);
            dt = fmaf(xt.z, yt.z, dt); dt = fmaf(xt.w, yt.w, dt);
        }
        float d = ds / (nrm[i] * nrm[j]) - dt / (nrm[K + i] * nrm[K + j]);
        acc = d * d;
    }

    red[tid] = acc;
    __syncthreads();
    for (int s = NT / 2; s > 0; s >>= 1) {
        if (tid < s) red[tid] += red[tid + s];
        __syncthreads();
    }
    if (tid == 0)
        atomicAdd(out, red[0] * (1.0f / (2.0f * K * K)));
}

extern "C" void kernel_launch(void* const* d_in, const int* in_sizes, int n_in,
                              void* d_out, int out_size, void* d_ws, size_t ws_size,
                              hipStream_t stream) {
    const float* S   = (const float*)d_in[0];
    const float* T   = (const float*)d_in[1];
    const int*   lbl = (const int*)d_in[2];
    float* out = (float*)d_out;

    float* sumsS = (float*)d_ws;                        // [2*512*19]
    float* sumsT = sumsS + (size_t)2 * NUM_C * K;

    // sums are atomicAdd targets, out is atomicAdd target: zero both (ws/out
    // are re-poisoned to 0xAA before every timed launch).
    hipMemsetAsync(d_ws, 0, (size_t)2 * 2 * NUM_C * K * sizeof(float), stream);
    hipMemsetAsync(d_out, 0, sizeof(float), stream);

    seg_sum_mfma<<<2 * 32 * CH, NT, 0, stream>>>(S, T, lbl, sumsS, sumsT);
    finalize_kernel<<<8, NT, 0, stream>>>(sumsS, sumsT, lbl, out);
}

// Round 5
// 335.378 us; speedup vs baseline: 1.0075x; 1.0075x over previous
//
#include <hip/hip_runtime.h>

#define NUM_C 512
#define HW    32768     // 128*256
#define K     19
#define NT    256
#define CP    (NUM_C + 4)
#define CH    16        // pixel chunks per (b, mtile)
#define W     256       // window pixels staged per iteration
#define WP    260       // LDS row stride in u32 (multiple of 4 for b128 align; 2-way banks = free)
#define NW    (HW / CH / W)   // 8 windows per block

typedef __attribute__((ext_vector_type(4))) float        f32x4;
typedef __attribute__((ext_vector_type(8))) short        bf16x8;
typedef __attribute__((ext_vector_type(4))) unsigned int u32x4;

// fp32 -> packed (hi_bf16 | lo_bf16<<16); hi = truncation, lo = RNE(x - hi).
__device__ __forceinline__ unsigned int cvt_hilo(float x) {
    unsigned int u  = __float_as_uint(x);
    float        d  = x - __uint_as_float(u & 0xFFFF0000u);
    unsigned int v  = __float_as_uint(d);
    unsigned int lo = (v + 0x7FFFu + ((v >> 16) & 1u)) & 0xFFFF0000u;
    return (u >> 16) | lo;
}

// ---------------------------------------------------------------------------
// K1: sums[b,c,k] = sum_hw feat * onehot(lbl) as MFMA GEMM, staged via LDS.
// R4 was memory-bound at 1.9 TB/s because each wave-load touched 16 scattered
// 64B segments (128KB-strided rows). Here every global load is 1KB contiguous
// from one row; the channel-major transpose the A-fragment needs happens in
// LDS (packed hi/lo bf16 u32, so ds_read_b128 IS the A-frag).
// grid = 2 x 32 mtiles x 16 chunks = 1024 blocks x 256 thr (4 waves).
// ---------------------------------------------------------------------------
__global__ __launch_bounds__(NT, 4) void seg_sum_mfma(
    const float* __restrict__ S, const float* __restrict__ T,
    const int* __restrict__ lbl,
    float* __restrict__ sumsS, float* __restrict__ sumsT)
{
    __shared__ unsigned int tile[32 * WP + W];   // [0,16*WP) S rows, [16*WP,32*WP) T rows, labels at 32*WP
    const int tid   = threadIdx.x;
    const int lane  = tid & 63, wv = tid >> 6;
    const int bid   = blockIdx.x;
    const int chunk = bid & (CH - 1);
    const int mtile = (bid >> 4) & 31;
    const int b     = bid >> 9;

    const int n = lane & 15;    // A row (channel-in-mtile) / class col
    const int q = lane >> 4;    // k-group

    const size_t rowbase = (size_t)(b * NUM_C + mtile * 16) * HW;
    const int    pixbase = chunk * (HW / CH);
    const int*   lrow    = lbl + (size_t)b * HW;

    f32x4 accS0 = {0.f,0.f,0.f,0.f}, accS1 = {0.f,0.f,0.f,0.f};
    f32x4 accT0 = {0.f,0.f,0.f,0.f}, accT1 = {0.f,0.f,0.f,0.f};

    for (int win = 0; win < NW; ++win) {
        const int pb = pixbase + win * W;

        // ---- stage: 32 one-row 1KB segments, 8 per wave, cvt to hi/lo bf16 ----
#pragma unroll
        for (int i = 0; i < 8; ++i) {
            const int seg    = wv * 8 + i;         // = tensor*16 + ch
            const int tensor = seg >> 4;
            const int ch     = seg & 15;
            const float* src = (tensor ? T : S) + rowbase + (size_t)ch * HW + pb;
            f32x4 x = ((const f32x4*)src)[lane];   // 64 lanes x 16B = 1KB contiguous
            u32x4 u;
            u.x = cvt_hilo(x.x); u.y = cvt_hilo(x.y);
            u.z = cvt_hilo(x.z); u.w = cvt_hilo(x.w);
            *(u32x4*)&tile[seg * WP + 4 * lane] = u;
        }
        tile[32 * WP + tid] = (unsigned)lrow[pb + tid];
        __syncthreads();

        // ---- consume: wave covers pixels [wv*64, wv*64+64) = 4 MFMA steps ----
#pragma unroll
        for (int s = 0; s < 4; ++s) {
            const int p0 = wv * 64 + s * 16 + 4 * q;   // this lane's 4 pixels
            bf16x8 aS = __builtin_bit_cast(bf16x8, *(const u32x4*)&tile[n * WP + p0]);
            bf16x8 aT = __builtin_bit_cast(bf16x8, *(const u32x4*)&tile[(16 + n) * WP + p0]);
            int4   lv = *(const int4*)&tile[32 * WP + p0];

            u32x4 w0, w1;   // one-hot duplicated into both bf16 halves (hi & lo k-slot)
            w0.x = (lv.x == n)      ? 0x3F803F80u : 0u;
            w0.y = (lv.y == n)      ? 0x3F803F80u : 0u;
            w0.z = (lv.z == n)      ? 0x3F803F80u : 0u;
            w0.w = (lv.w == n)      ? 0x3F803F80u : 0u;
            w1.x = (lv.x == n + 16) ? 0x3F803F80u : 0u;
            w1.y = (lv.y == n + 16) ? 0x3F803F80u : 0u;
            w1.z = (lv.z == n + 16) ? 0x3F803F80u : 0u;
            w1.w = (lv.w == n + 16) ? 0x3F803F80u : 0u;
            bf16x8 fb0 = __builtin_bit_cast(bf16x8, w0);
            bf16x8 fb1 = __builtin_bit_cast(bf16x8, w1);

            accS0 = __builtin_amdgcn_mfma_f32_16x16x32_bf16(aS, fb0, accS0, 0, 0, 0);
            accS1 = __builtin_amdgcn_mfma_f32_16x16x32_bf16(aS, fb1, accS1, 0, 0, 0);
            accT0 = __builtin_amdgcn_mfma_f32_16x16x32_bf16(aT, fb0, accT0, 0, 0, 0);
            accT1 = __builtin_amdgcn_mfma_f32_16x16x32_bf16(aT, fb1, accT1, 0, 0, 0);
        }
        __syncthreads();   // tile reused next window
    }

    // ---- cross-wave reduce (red buffer overlaid on tile), then atomicAdd ----
    // per-wave layout: [0,256) S-t0 (row*16+col), [256,304) S-t1 (row*3+col'),
    // [304,560) T-t0, [560,608) T-t1.  (C/D: col=lane&15, row=q*4+r -- verified R4)
    float* red = (float*)tile;
#pragma unroll
    for (int r = 0; r < 4; ++r) {
        const int row = q * 4 + r;
        red[wv * 608 + row * 16 + n]       = accS0[r];
        red[wv * 608 + 304 + row * 16 + n] = accT0[r];
    }
    if (n < 3) {
#pragma unroll
        for (int r = 0; r < 4; ++r) {
            const int row = q * 4 + r;
            red[wv * 608 + 256 + row * 3 + n] = accS1[r];
            red[wv * 608 + 560 + row * 3 + n] = accT1[r];
        }
    }
    __syncthreads();

    for (int t = tid; t < 608; t += NT) {
        float v = red[t] + red[608 + t] + red[1216 + t] + red[1824 + t];
        const int tensor = t / 304;
        const int r = t - tensor * 304;
        int row, col;
        if (r < 256) { row = r >> 4; col = r & 15; }
        else         { const int rr = r - 256; row = rr / 3; col = 16 + (rr - (rr / 3) * 3); }
        float* dst = (tensor ? sumsT : sumsS)
                   + (size_t)(b * NUM_C + mtile * 16 + row) * K + col;
        atomicAdd(dst, v);   // 16 chunk-writers per address
    }
}

// ---------------------------------------------------------------------------
// K2: grid = 8 blocks = 2 batches x 4 slices (unchanged from R4 -- not the
// bottleneck). counts -> centers -> diagonal norms -> 361 pair tasks.
// ---------------------------------------------------------------------------
__global__ __launch_bounds__(NT, 4) void finalize_kernel(
    const float* __restrict__ sumsS, const float* __restrict__ sumsT,
    const int* __restrict__ lbl, float* __restrict__ out)
{
    __shared__ float centS[K * CP];
    __shared__ float centT[K * CP];
    __shared__ float cntf[K];
    __shared__ float nrm[2 * K];
    __shared__ float red[NT];
    __shared__ int   redc[4 * K];
    const int tid   = threadIdx.x;
    const int b     = blockIdx.x >> 2;
    const int slice = blockIdx.x & 3;

    int cnt[K];
#pragma unroll
    for (int k = 0; k < K; ++k) cnt[k] = 0;
    const int4* L4 = (const int4*)(lbl + (size_t)b * HW);
    for (int i = tid; i < HW / 4; i += NT) {
        int4 l = L4[i];
#pragma unroll
        for (int k = 0; k < K; ++k)
            cnt[k] += (l.x == k) + (l.y == k) + (l.z == k) + (l.w == k);
    }
    const int lane = tid & 63, wv = tid >> 6;
#pragma unroll
    for (int k = 0; k < K; ++k) {
        int v = cnt[k];
#pragma unroll
        for (int off = 32; off > 0; off >>= 1) v += __shfl_down(v, off);
        if (lane == 0) redc[wv * K + k] = v;
    }
    __syncthreads();
    if (tid < K)
        cntf[tid] = (float)(redc[tid] + redc[K + tid] + redc[2 * K + tid] + redc[3 * K + tid]) + 1e-6f;
    __syncthreads();

    for (int j = tid; j < NUM_C * K; j += NT) {
        int c = j / K, k = j - (j / K) * K;
        float cn = cntf[k];
        size_t gi = (size_t)(b * NUM_C + c) * K + k;
        centS[k * CP + c] = sumsS[gi] / cn;
        centT[k * CP + c] = sumsT[gi] / cn;
    }
    __syncthreads();

    if (tid < 2 * K) {
        const float4* A = (const float4*)((tid < K ? centS : centT) + (tid < K ? tid : tid - K) * CP);
        float d = 0.f;
        for (int c = 0; c < NUM_C / 4; ++c) {
            float4 x = A[c];
            d = fmaf(x.x, x.x, d); d = fmaf(x.y, x.y, d);
            d = fmaf(x.z, x.z, d); d = fmaf(x.w, x.w, d);
        }
        nrm[tid] = fmaxf(sqrtf(d), 1e-8f);
    }
    __syncthreads();

    float acc = 0.f;
    int t = tid * 4 + slice;
    if (t < K * K) {
        int i = t / K, j = t - (t / K) * K;
        const float4* Si = (const float4*)(centS + i * CP);
        const float4* Sj = (const float4*)(centS + j * CP);
        const float4* Ti = (const float4*)(centT + i * CP);
        const float4* Tj = (const float4*)(centT + j * CP);
        float ds = 0.f, dt = 0.f;
        for (int c = 0; c < NUM_C / 4; ++c) {
            float4 xs = Si[c], ys = Sj[c];
            float4 xt = Ti[c], yt = Tj[c];
            ds = fmaf(xs.x, ys.x, ds); ds = fmaf(xs.y, ys.y, ds);
            ds = fmaf(xs.z, ys.z, ds); ds = fmaf(xs.w, ys.w, ds);
            dt = fmaf(xt.x, yt.x, dt); dt = fmaf(xt.y, yt.y, dt);
            dt = fmaf(xt.z, yt.z, dt); dt = fmaf(xt.w, yt.w, dt);
        }
        float d = ds / (nrm[i] * nrm[j]) - dt / (nrm[K + i] * nrm[K + j]);
        acc = d * d;
    }

    red[tid] = acc;
    __syncthreads();
    for (int s = NT / 2; s > 0; s >>= 1) {
        if (tid < s) red[tid] += red[tid + s];
        __syncthreads();
    }
    if (tid == 0)
        atomicAdd(out, red[0] * (1.0f / (2.0f * K * K)));
}

extern "C" void kernel_launch(void* const* d_in, const int* in_sizes, int n_in,
                              void* d_out, int out_size, void* d_ws, size_t ws_size,
                              hipStream_t stream) {
    const float* S   = (const float*)d_in[0];
    const float* T   = (const float*)d_in[1];
    const int*   lbl = (const int*)d_in[2];
    float* out = (float*)d_out;

    float* sumsS = (float*)d_ws;                        // [2*512*19]
    float* sumsT = sumsS + (size_t)2 * NUM_C * K;

    hipMemsetAsync(d_ws, 0, (size_t)2 * 2 * NUM_C * K * sizeof(float), stream);
    hipMemsetAsync(d_out, 0, sizeof(float), stream);

    seg_sum_mfma<<<2 * 32 * CH, NT, 0, stream>>>(S, T, lbl, sumsS, sumsT);
    finalize_kernel<<<8, NT, 0, stream>>>(sumsS, sumsT, lbl, out);
}